// Round 4
// baseline (232.749 us; speedup 1.0000x reference)
//
#include <hip/hip_runtime.h>

// Shapes: tarsent [8,512,512] f32, tar_func [8,512] i32,
//         refsent [8,32,256,512] f32, ref_func [8,32,256] i32.
// Output flat-concat f32 (masks as 0.0/1.0):
//   tar_aug[8,5,512]@0  tar_aug_mask[8,5]@20480  ref_aug[8,32,5,512]@20520
//   ref_aug_mask[8,32,5]@675880  tarpaper[8,512]@677160  tar_mask2[8]@681256
//   refpaper[8,32,512]@681264  ref_mask2[8,32]@812336   total 812592

#define H      512
#define HV     128
#define NL     5
#define BIGF   1e11f
#define CHUNK  64
#define NITER  (CHUNK / 2)     // 32 sentences per thread (phase-strided)

#define OFF_TAR_AUG       0
#define OFF_TAR_AUG_MASK  20480
#define OFF_REF_AUG       20520
#define OFF_REF_AUG_MASK  675880
#define OFF_TARPAPER      677160
#define OFF_TAR_MASK2     681256
#define OFF_REFPAPER      681264
#define OFF_REF_MASK2     812336

#define NCHUNK_REF 4       // 256 / 64
#define NCHUNK_TAR 8       // 512 / 64
#define NBLK_REF   1024    // 256 segs * 4
#define NBLK1      1088    // + 8 segs * 8
#define WSUM_ELEMS ((size_t)NBLK1 * NL * H)      // 2,785,280 f32 = 11.1 MB
#define WCNT_OFF_B (WSUM_ELEMS * 4)
#define WS_NEED    (WCNT_OFF_B + (size_t)NBLK1 * NL * 4)

__device__ inline float4 f4add(float4 a, float4 b) {
    a.x += b.x; a.y += b.y; a.z += b.z; a.w += b.w; return a;
}
__device__ inline float4 f4scale(float4 a, float s) {
    a.x *= s; a.y *= s; a.z *= s; a.w *= s; return a;
}
__device__ inline void accum(int l, float4 v,
                             float4& a1, float4& a2, float4& a3,
                             float4& a4, float4& a5,
                             int& c1, int& c2, int& c3, int& c4, int& c5) {
    // l is wave-uniform (readfirstlane'd) -> scalar-pipe branches
    if      (l == 1) { a1 = f4add(a1, v); c1++; }
    else if (l == 2) { a2 = f4add(a2, v); c2++; }
    else if (l == 3) { a3 = f4add(a3, v); c3++; }
    else if (l == 4) { a4 = f4add(a4, v); c4++; }
    else if (l == 5) { a5 = f4add(a5, v); c5++; }
}

// ---------------- Stage 1: per-(segment,chunk) partial label sums ----------
// b < 1024: ref  seg=b>>2, chunk=b&3.   b >= 1024: tar  seg=q>>3, chunk=q&7.
__global__ __launch_bounds__(256) void emenc_stage1(
    const float* __restrict__ tar_state, const int* __restrict__ tar_func,
    const float* __restrict__ ref_state, const int* __restrict__ ref_func,
    float* __restrict__ wsum, int* __restrict__ wcnt)
{
    __shared__ int    sfunc[CHUNK];
    __shared__ float4 spart[HV * NL];
    __shared__ int    scnt[NL];

    const int b = blockIdx.x;
    const float* state;
    const int*   func;
    int s0;
    if (b < NBLK_REF) {
        const int seg = b >> 2, ch = b & 3;
        state = ref_state + (size_t)seg * 256 * H;
        func  = ref_func  + seg * 256;
        s0    = ch * CHUNK;
    } else {
        const int q = b - NBLK_REF;
        const int seg = q >> 3, ch = q & 7;
        state = tar_state + (size_t)seg * 512 * H;
        func  = tar_func  + seg * 512;
        s0    = ch * CHUNK;
    }

    const int tid = threadIdx.x;
    if (tid < CHUNK) sfunc[tid] = func[s0 + tid];
    __syncthreads();

    const int col   = tid & (HV - 1);
    const int phase = tid >> 7;

    // Preload ALL labels for this thread's sentences; readfirstlane makes them
    // wave-uniform scalars (labels are per-sentence; waves are phase-aligned,
    // so all 64 lanes see the same sentence index). This takes the ds_read
    // off the inner loop's critical path.
    int lab[NITER];
    #pragma unroll
    for (int j = 0; j < NITER; j++)
        lab[j] = __builtin_amdgcn_readfirstlane(sfunc[2 * j + phase]);

    float4 a1 = {0,0,0,0}, a2 = {0,0,0,0}, a3 = {0,0,0,0},
           a4 = {0,0,0,0}, a5 = {0,0,0,0};
    int c1 = 0, c2 = 0, c3 = 0, c4 = 0, c5 = 0;

    // column pointer: element j lives at row (2j+phase) of the chunk
    const float4* colp = ((const float4*)(state + (size_t)s0 * H)) + col
                         + (size_t)phase * HV;

    // 4 batches of 8: issue 8 independent dwordx4 loads, then consume.
    #pragma unroll
    for (int batch = 0; batch < NITER / 8; ++batch) {
        const int j0 = batch * 8;
        float4 v0 = colp[(size_t)(2 * (j0 + 0)) * HV];
        float4 v1 = colp[(size_t)(2 * (j0 + 1)) * HV];
        float4 v2 = colp[(size_t)(2 * (j0 + 2)) * HV];
        float4 v3 = colp[(size_t)(2 * (j0 + 3)) * HV];
        float4 v4 = colp[(size_t)(2 * (j0 + 4)) * HV];
        float4 v5 = colp[(size_t)(2 * (j0 + 5)) * HV];
        float4 v6 = colp[(size_t)(2 * (j0 + 6)) * HV];
        float4 v7 = colp[(size_t)(2 * (j0 + 7)) * HV];
        accum(lab[j0 + 0], v0, a1, a2, a3, a4, a5, c1, c2, c3, c4, c5);
        accum(lab[j0 + 1], v1, a1, a2, a3, a4, a5, c1, c2, c3, c4, c5);
        accum(lab[j0 + 2], v2, a1, a2, a3, a4, a5, c1, c2, c3, c4, c5);
        accum(lab[j0 + 3], v3, a1, a2, a3, a4, a5, c1, c2, c3, c4, c5);
        accum(lab[j0 + 4], v4, a1, a2, a3, a4, a5, c1, c2, c3, c4, c5);
        accum(lab[j0 + 5], v5, a1, a2, a3, a4, a5, c1, c2, c3, c4, c5);
        accum(lab[j0 + 6], v6, a1, a2, a3, a4, a5, c1, c2, c3, c4, c5);
        accum(lab[j0 + 7], v7, a1, a2, a3, a4, a5, c1, c2, c3, c4, c5);
    }

    if (phase == 1) {
        spart[col * NL + 0] = a1;
        spart[col * NL + 1] = a2;
        spart[col * NL + 2] = a3;
        spart[col * NL + 3] = a4;
        spart[col * NL + 4] = a5;
        if (col == 0) {
            scnt[0] = c1; scnt[1] = c2; scnt[2] = c3; scnt[3] = c4; scnt[4] = c5;
        }
    }
    __syncthreads();

    if (phase == 0) {
        a1 = f4add(a1, spart[col * NL + 0]);
        a2 = f4add(a2, spart[col * NL + 1]);
        a3 = f4add(a3, spart[col * NL + 2]);
        a4 = f4add(a4, spart[col * NL + 3]);
        a5 = f4add(a5, spart[col * NL + 4]);

        float* wb = wsum + (size_t)b * NL * H;
        ((float4*)(wb + 0 * H))[col] = a1;
        ((float4*)(wb + 1 * H))[col] = a2;
        ((float4*)(wb + 2 * H))[col] = a3;
        ((float4*)(wb + 3 * H))[col] = a4;
        ((float4*)(wb + 4 * H))[col] = a5;

        if (col == 0) {
            wcnt[b * NL + 0] = c1 + scnt[0];
            wcnt[b * NL + 1] = c2 + scnt[1];
            wcnt[b * NL + 2] = c3 + scnt[2];
            wcnt[b * NL + 3] = c4 + scnt[3];
            wcnt[b * NL + 4] = c5 + scnt[4];
        }
    }
}

// ---------------- Stage 2: one block per (segment, role) ------------------
// role 0..4 -> aug label; role 5 -> paper + mask2. 128 threads = cols.
__global__ __launch_bounds__(128) void emenc_stage2(
    const float* __restrict__ wsum, const int* __restrict__ wcnt,
    float* __restrict__ out)
{
    const int bb   = blockIdx.x;
    const int seg  = bb / 6;
    const int role = bb - seg * 6;

    int nch, wb0;
    float *aug, *augmask, *paper, *mask2;
    if (seg < 256) {
        nch = NCHUNK_REF; wb0 = seg * NCHUNK_REF;
        aug     = out + OFF_REF_AUG      + (size_t)seg * NL * H;
        augmask = out + OFF_REF_AUG_MASK + seg * NL;
        paper   = out + OFF_REFPAPER     + (size_t)seg * H;
        mask2   = out + OFF_REF_MASK2    + seg;
    } else {
        const int q = seg - 256;
        nch = NCHUNK_TAR; wb0 = NBLK_REF + q * NCHUNK_TAR;
        aug     = out + OFF_TAR_AUG      + (size_t)q * NL * H;
        augmask = out + OFF_TAR_AUG_MASK + q * NL;
        paper   = out + OFF_TARPAPER     + (size_t)q * H;
        mask2   = out + OFF_TAR_MASK2    + q;
    }

    const int col = threadIdx.x;

    if (role < NL) {
        int c = 0;
        for (int ch = 0; ch < nch; ch++) c += wcnt[(wb0 + ch) * NL + role];
        float4 s = {0,0,0,0};
        for (int ch = 0; ch < nch; ch++)
            s = f4add(s, ((const float4*)(wsum + (size_t)(wb0 + ch) * NL * H
                                          + (size_t)role * H))[col]);
        const float inv = 1.0f / (c > 0 ? (float)c : BIGF);
        ((float4*)(aug + (size_t)role * H))[col] = f4scale(s, inv);
        if (col == 0) augmask[role] = c > 0 ? 1.0f : 0.0f;
    } else {
        int ct = 0;
        for (int ch = 0; ch < nch; ch++) {
            #pragma unroll
            for (int l = 0; l < NL; l++) ct += wcnt[(wb0 + ch) * NL + l];
        }
        float4 t = {0,0,0,0};
        for (int ch = 0; ch < nch; ch++) {
            const float4* wb = (const float4*)(wsum + (size_t)(wb0 + ch) * NL * H);
            #pragma unroll
            for (int l = 0; l < NL; l++) t = f4add(t, wb[l * HV + col]);
        }
        ((float4*)paper)[col] = f4scale(t, 1.0f / (ct > 0 ? (float)ct : BIGF));
        if (col == 0) mask2[0] = ct > 0 ? 1.0f : 0.0f;
    }
}

// ---------------- Fallback (single-stage) if ws too small ------------------
__global__ __launch_bounds__(256) void emenc_single(
    const float* __restrict__ tar_state, const int* __restrict__ tar_func,
    const float* __restrict__ ref_state, const int* __restrict__ ref_func,
    float* __restrict__ out)
{
    __shared__ int    sfunc[512];
    __shared__ float4 spart[HV * NL];
    __shared__ int    scnt[NL];

    const int b = blockIdx.x;
    const float* state;
    const int*   func;
    int S;
    float *aug, *augmask, *paper, *mask2;

    if (b < 256) {
        state   = ref_state + (size_t)b * 256 * H;
        func    = ref_func  + b * 256;
        S       = 256;
        aug     = out + OFF_REF_AUG      + (size_t)b * NL * H;
        augmask = out + OFF_REF_AUG_MASK + b * NL;
        paper   = out + OFF_REFPAPER     + (size_t)b * H;
        mask2   = out + OFF_REF_MASK2    + b;
    } else {
        const int q = b - 256;
        state   = tar_state + (size_t)q * 512 * H;
        func    = tar_func  + q * 512;
        S       = 512;
        aug     = out + OFF_TAR_AUG      + (size_t)q * NL * H;
        augmask = out + OFF_TAR_AUG_MASK + q * NL;
        paper   = out + OFF_TARPAPER     + (size_t)q * H;
        mask2   = out + OFF_TAR_MASK2    + q;
    }

    const int tid = threadIdx.x;
    for (int i = tid; i < S; i += 256) sfunc[i] = func[i];
    __syncthreads();

    const int col   = tid & (HV - 1);
    const int phase = tid >> 7;

    float4 a1 = {0,0,0,0}, a2 = {0,0,0,0}, a3 = {0,0,0,0},
           a4 = {0,0,0,0}, a5 = {0,0,0,0};
    int c1 = 0, c2 = 0, c3 = 0, c4 = 0, c5 = 0;

    #pragma unroll 4
    for (int s = phase; s < S; s += 2) {
        float4 v = ((const float4*)(state + (size_t)s * H))[col];
        int l = __builtin_amdgcn_readfirstlane(sfunc[s]);
        accum(l, v, a1, a2, a3, a4, a5, c1, c2, c3, c4, c5);
    }

    if (phase == 1) {
        spart[col * NL + 0] = a1;
        spart[col * NL + 1] = a2;
        spart[col * NL + 2] = a3;
        spart[col * NL + 3] = a4;
        spart[col * NL + 4] = a5;
        if (col == 0) {
            scnt[0] = c1; scnt[1] = c2; scnt[2] = c3; scnt[3] = c4; scnt[4] = c5;
        }
    }
    __syncthreads();

    if (phase == 0) {
        a1 = f4add(a1, spart[col * NL + 0]);
        a2 = f4add(a2, spart[col * NL + 1]);
        a3 = f4add(a3, spart[col * NL + 2]);
        a4 = f4add(a4, spart[col * NL + 3]);
        a5 = f4add(a5, spart[col * NL + 4]);
        c1 += scnt[0]; c2 += scnt[1]; c3 += scnt[2]; c4 += scnt[3]; c5 += scnt[4];

        float4 t  = f4add(f4add(f4add(a1, a2), f4add(a3, a4)), a5);
        const int ct = c1 + c2 + c3 + c4 + c5;

        ((float4*)(aug + 0 * H))[col] = f4scale(a1, 1.0f / (c1 > 0 ? (float)c1 : BIGF));
        ((float4*)(aug + 1 * H))[col] = f4scale(a2, 1.0f / (c2 > 0 ? (float)c2 : BIGF));
        ((float4*)(aug + 2 * H))[col] = f4scale(a3, 1.0f / (c3 > 0 ? (float)c3 : BIGF));
        ((float4*)(aug + 3 * H))[col] = f4scale(a4, 1.0f / (c4 > 0 ? (float)c4 : BIGF));
        ((float4*)(aug + 4 * H))[col] = f4scale(a5, 1.0f / (c5 > 0 ? (float)c5 : BIGF));
        ((float4*)paper)[col]         = f4scale(t,  1.0f / (ct > 0 ? (float)ct : BIGF));

        if (col == 0) {
            augmask[0] = c1 > 0 ? 1.0f : 0.0f;
            augmask[1] = c2 > 0 ? 1.0f : 0.0f;
            augmask[2] = c3 > 0 ? 1.0f : 0.0f;
            augmask[3] = c4 > 0 ? 1.0f : 0.0f;
            augmask[4] = c5 > 0 ? 1.0f : 0.0f;
            mask2[0]   = ct > 0 ? 1.0f : 0.0f;
        }
    }
}

extern "C" void kernel_launch(void* const* d_in, const int* in_sizes, int n_in,
                              void* d_out, int out_size, void* d_ws, size_t ws_size,
                              hipStream_t stream) {
    const float* tar_state = (const float*)d_in[0];
    const int*   tar_func  = (const int*)d_in[1];
    const float* ref_state = (const float*)d_in[2];
    const int*   ref_func  = (const int*)d_in[3];
    float* out = (float*)d_out;

    if (ws_size >= WS_NEED) {
        float* wsum = (float*)d_ws;
        int*   wcnt = (int*)((char*)d_ws + WCNT_OFF_B);
        emenc_stage1<<<NBLK1, 256, 0, stream>>>(tar_state, tar_func,
                                                ref_state, ref_func, wsum, wcnt);
        emenc_stage2<<<264 * 6, 128, 0, stream>>>(wsum, wcnt, out);
    } else {
        emenc_single<<<264, 256, 0, stream>>>(tar_state, tar_func,
                                              ref_state, ref_func, out);
    }
}

// Round 5
// 210.709 us; speedup vs baseline: 1.1046x; 1.1046x over previous
//
#include <hip/hip_runtime.h>

// Shapes: tarsent [8,512,512] f32, tar_func [8,512] i32,
//         refsent [8,32,256,512] f32, ref_func [8,32,256] i32.
// Output flat-concat f32 (masks as 0.0/1.0):
//   tar_aug[8,5,512]@0  tar_aug_mask[8,5]@20480  ref_aug[8,32,5,512]@20520
//   ref_aug_mask[8,32,5]@675880  tarpaper[8,512]@677160  tar_mask2[8]@681256
//   refpaper[8,32,512]@681264  ref_mask2[8,32]@812336   total 812592

#define H      512
#define HV     128
#define NL     5
#define BIGF   1e11f
#define CHUNK  64
#define NITER  (CHUNK / 2)     // 32 rows per thread (phase-strided)
#define BATCH  8

#define OFF_TAR_AUG       0
#define OFF_TAR_AUG_MASK  20480
#define OFF_REF_AUG       20520
#define OFF_REF_AUG_MASK  675880
#define OFF_TARPAPER      677160
#define OFF_TAR_MASK2     681256
#define OFF_REFPAPER      681264
#define OFF_REF_MASK2     812336

#define NCHUNK_REF 4       // 256 / 64
#define NCHUNK_TAR 8       // 512 / 64
#define NBLK_REF   1024    // 256 segs * 4
#define NBLK1      1088    // + 8 segs * 8
#define WSUM_ELEMS ((size_t)NBLK1 * NL * H)      // 11.1 MB
#define WCNT_OFF_B (WSUM_ELEMS * 4)
#define WS_NEED    (WCNT_OFF_B + (size_t)NBLK1 * NL * 4)

__device__ inline float4 f4add(float4 a, float4 b) {
    a.x += b.x; a.y += b.y; a.z += b.z; a.w += b.w; return a;
}
__device__ inline float4 f4scale(float4 a, float s) {
    a.x *= s; a.y *= s; a.z *= s; a.w *= s; return a;
}
__device__ inline float4 f4fma(float w, float4 v, float4 a) {
    a.x = fmaf(w, v.x, a.x); a.y = fmaf(w, v.y, a.y);
    a.z = fmaf(w, v.z, a.z); a.w = fmaf(w, v.w, a.w); return a;
}

// ---------------- Stage 1: per-(segment,chunk) partial label sums ----------
// Branchless: w_l = (lab==l), acc_l = fma(w_l, v, acc_l). No control flow in
// the hot loop -> no spills, loads batched 8-deep and fully independent.
__global__ __launch_bounds__(256) void emenc_stage1(
    const float* __restrict__ tar_state, const int* __restrict__ tar_func,
    const float* __restrict__ ref_state, const int* __restrict__ ref_func,
    float* __restrict__ wsum, int* __restrict__ wcnt)
{
    __shared__ int    sfunc[CHUNK];
    __shared__ float4 spart[HV * NL];

    const int b = blockIdx.x;
    const float* state;
    const int*   func;
    int s0;
    if (b < NBLK_REF) {
        const int seg = b >> 2, ch = b & 3;
        state = ref_state + (size_t)seg * 256 * H;
        func  = ref_func  + seg * 256;
        s0    = ch * CHUNK;
    } else {
        const int q = b - NBLK_REF;
        const int seg = q >> 3, ch = q & 7;
        state = tar_state + (size_t)seg * 512 * H;
        func  = tar_func  + seg * 512;
        s0    = ch * CHUNK;
    }

    const int tid = threadIdx.x;
    if (tid < CHUNK) sfunc[tid] = func[s0 + tid];
    __syncthreads();

    const int col   = tid & (HV - 1);
    const int phase = tid >> 7;

    float4 a1 = {0,0,0,0}, a2 = {0,0,0,0}, a3 = {0,0,0,0},
           a4 = {0,0,0,0}, a5 = {0,0,0,0};

    const float4* colp = ((const float4*)(state + (size_t)s0 * H)) + col
                         + (size_t)phase * HV;

    #pragma unroll
    for (int batch = 0; batch < NITER / BATCH; ++batch) {
        const int j0 = batch * BATCH;
        float4 v[BATCH];
        int    lb[BATCH];
        #pragma unroll
        for (int k = 0; k < BATCH; ++k)
            v[k] = colp[(size_t)(2 * (j0 + k)) * HV];
        #pragma unroll
        for (int k = 0; k < BATCH; ++k)
            lb[k] = sfunc[2 * (j0 + k) + phase];
        #pragma unroll
        for (int k = 0; k < BATCH; ++k) {
            const int l = lb[k];
            const float w1 = (l == 1) ? 1.0f : 0.0f;
            const float w2 = (l == 2) ? 1.0f : 0.0f;
            const float w3 = (l == 3) ? 1.0f : 0.0f;
            const float w4 = (l == 4) ? 1.0f : 0.0f;
            const float w5 = (l == 5) ? 1.0f : 0.0f;
            a1 = f4fma(w1, v[k], a1);
            a2 = f4fma(w2, v[k], a2);
            a3 = f4fma(w3, v[k], a3);
            a4 = f4fma(w4, v[k], a4);
            a5 = f4fma(w5, v[k], a5);
        }
    }

    if (phase == 1) {
        spart[col * NL + 0] = a1;
        spart[col * NL + 1] = a2;
        spart[col * NL + 2] = a3;
        spart[col * NL + 3] = a4;
        spart[col * NL + 4] = a5;
    }
    __syncthreads();

    if (phase == 0) {
        a1 = f4add(a1, spart[col * NL + 0]);
        a2 = f4add(a2, spart[col * NL + 1]);
        a3 = f4add(a3, spart[col * NL + 2]);
        a4 = f4add(a4, spart[col * NL + 3]);
        a5 = f4add(a5, spart[col * NL + 4]);

        float* wb = wsum + (size_t)b * NL * H;
        ((float4*)(wb + 0 * H))[col] = a1;
        ((float4*)(wb + 1 * H))[col] = a2;
        ((float4*)(wb + 2 * H))[col] = a3;
        ((float4*)(wb + 3 * H))[col] = a4;
        ((float4*)(wb + 4 * H))[col] = a5;
    }

    // counts depend only on labels: 5 threads scan LDS
    if (tid < NL) {
        int c = 0;
        #pragma unroll
        for (int i = 0; i < CHUNK; ++i) c += (sfunc[i] == tid + 1) ? 1 : 0;
        wcnt[b * NL + tid] = c;
    }
}

// ---------------- Stage 2: one block per (segment, role) ------------------
// role 0..4 -> aug label; role 5 -> paper + mask2. 128 threads = cols.
__global__ __launch_bounds__(128) void emenc_stage2(
    const float* __restrict__ wsum, const int* __restrict__ wcnt,
    float* __restrict__ out)
{
    const int bb   = blockIdx.x;
    const int seg  = bb / 6;
    const int role = bb - seg * 6;

    int nch, wb0;
    float *aug, *augmask, *paper, *mask2;
    if (seg < 256) {
        nch = NCHUNK_REF; wb0 = seg * NCHUNK_REF;
        aug     = out + OFF_REF_AUG      + (size_t)seg * NL * H;
        augmask = out + OFF_REF_AUG_MASK + seg * NL;
        paper   = out + OFF_REFPAPER     + (size_t)seg * H;
        mask2   = out + OFF_REF_MASK2    + seg;
    } else {
        const int q = seg - 256;
        nch = NCHUNK_TAR; wb0 = NBLK_REF + q * NCHUNK_TAR;
        aug     = out + OFF_TAR_AUG      + (size_t)q * NL * H;
        augmask = out + OFF_TAR_AUG_MASK + q * NL;
        paper   = out + OFF_TARPAPER     + (size_t)q * H;
        mask2   = out + OFF_TAR_MASK2    + q;
    }

    const int col = threadIdx.x;

    if (role < NL) {
        int c = 0;
        for (int ch = 0; ch < nch; ch++) c += wcnt[(wb0 + ch) * NL + role];
        float4 s = {0,0,0,0};
        for (int ch = 0; ch < nch; ch++)
            s = f4add(s, ((const float4*)(wsum + (size_t)(wb0 + ch) * NL * H
                                          + (size_t)role * H))[col]);
        const float inv = 1.0f / (c > 0 ? (float)c : BIGF);
        ((float4*)(aug + (size_t)role * H))[col] = f4scale(s, inv);
        if (col == 0) augmask[role] = c > 0 ? 1.0f : 0.0f;
    } else {
        int ct = 0;
        for (int ch = 0; ch < nch; ch++) {
            #pragma unroll
            for (int l = 0; l < NL; l++) ct += wcnt[(wb0 + ch) * NL + l];
        }
        float4 t = {0,0,0,0};
        for (int ch = 0; ch < nch; ch++) {
            const float4* wb = (const float4*)(wsum + (size_t)(wb0 + ch) * NL * H);
            #pragma unroll
            for (int l = 0; l < NL; l++) t = f4add(t, wb[l * HV + col]);
        }
        ((float4*)paper)[col] = f4scale(t, 1.0f / (ct > 0 ? (float)ct : BIGF));
        if (col == 0) mask2[0] = ct > 0 ? 1.0f : 0.0f;
    }
}

// ---------------- Fallback (single-stage) if ws too small ------------------
__global__ __launch_bounds__(256) void emenc_single(
    const float* __restrict__ tar_state, const int* __restrict__ tar_func,
    const float* __restrict__ ref_state, const int* __restrict__ ref_func,
    float* __restrict__ out)
{
    __shared__ int    sfunc[512];
    __shared__ float4 spart[HV * NL];
    __shared__ int    scnt[NL];

    const int b = blockIdx.x;
    const float* state;
    const int*   func;
    int S;
    float *aug, *augmask, *paper, *mask2;

    if (b < 256) {
        state   = ref_state + (size_t)b * 256 * H;
        func    = ref_func  + b * 256;
        S       = 256;
        aug     = out + OFF_REF_AUG      + (size_t)b * NL * H;
        augmask = out + OFF_REF_AUG_MASK + b * NL;
        paper   = out + OFF_REFPAPER     + (size_t)b * H;
        mask2   = out + OFF_REF_MASK2    + b;
    } else {
        const int q = b - 256;
        state   = tar_state + (size_t)q * 512 * H;
        func    = tar_func  + q * 512;
        S       = 512;
        aug     = out + OFF_TAR_AUG      + (size_t)q * NL * H;
        augmask = out + OFF_TAR_AUG_MASK + q * NL;
        paper   = out + OFF_TARPAPER     + (size_t)q * H;
        mask2   = out + OFF_TAR_MASK2    + q;
    }

    const int tid = threadIdx.x;
    for (int i = tid; i < S; i += 256) sfunc[i] = func[i];
    __syncthreads();

    const int col   = tid & (HV - 1);
    const int phase = tid >> 7;

    float4 a1 = {0,0,0,0}, a2 = {0,0,0,0}, a3 = {0,0,0,0},
           a4 = {0,0,0,0}, a5 = {0,0,0,0};

    for (int s = phase; s < S; s += 2) {
        float4 v = ((const float4*)(state + (size_t)s * H))[col];
        const int l = sfunc[s];
        a1 = f4fma((l == 1) ? 1.0f : 0.0f, v, a1);
        a2 = f4fma((l == 2) ? 1.0f : 0.0f, v, a2);
        a3 = f4fma((l == 3) ? 1.0f : 0.0f, v, a3);
        a4 = f4fma((l == 4) ? 1.0f : 0.0f, v, a4);
        a5 = f4fma((l == 5) ? 1.0f : 0.0f, v, a5);
    }

    if (phase == 1) {
        spart[col * NL + 0] = a1;
        spart[col * NL + 1] = a2;
        spart[col * NL + 2] = a3;
        spart[col * NL + 3] = a4;
        spart[col * NL + 4] = a5;
    }
    if (tid < NL) {
        int c = 0;
        for (int i = 0; i < S; ++i) c += (sfunc[i] == tid + 1) ? 1 : 0;
        scnt[tid] = c;
    }
    __syncthreads();

    if (phase == 0) {
        a1 = f4add(a1, spart[col * NL + 0]);
        a2 = f4add(a2, spart[col * NL + 1]);
        a3 = f4add(a3, spart[col * NL + 2]);
        a4 = f4add(a4, spart[col * NL + 3]);
        a5 = f4add(a5, spart[col * NL + 4]);

        const int c1 = scnt[0], c2 = scnt[1], c3 = scnt[2],
                  c4 = scnt[3], c5 = scnt[4];
        float4 t  = f4add(f4add(f4add(a1, a2), f4add(a3, a4)), a5);
        const int ct = c1 + c2 + c3 + c4 + c5;

        ((float4*)(aug + 0 * H))[col] = f4scale(a1, 1.0f / (c1 > 0 ? (float)c1 : BIGF));
        ((float4*)(aug + 1 * H))[col] = f4scale(a2, 1.0f / (c2 > 0 ? (float)c2 : BIGF));
        ((float4*)(aug + 2 * H))[col] = f4scale(a3, 1.0f / (c3 > 0 ? (float)c3 : BIGF));
        ((float4*)(aug + 3 * H))[col] = f4scale(a4, 1.0f / (c4 > 0 ? (float)c4 : BIGF));
        ((float4*)(aug + 4 * H))[col] = f4scale(a5, 1.0f / (c5 > 0 ? (float)c5 : BIGF));
        ((float4*)paper)[col]         = f4scale(t,  1.0f / (ct > 0 ? (float)ct : BIGF));

        if (col == 0) {
            augmask[0] = c1 > 0 ? 1.0f : 0.0f;
            augmask[1] = c2 > 0 ? 1.0f : 0.0f;
            augmask[2] = c3 > 0 ? 1.0f : 0.0f;
            augmask[3] = c4 > 0 ? 1.0f : 0.0f;
            augmask[4] = c5 > 0 ? 1.0f : 0.0f;
            mask2[0]   = ct > 0 ? 1.0f : 0.0f;
        }
    }
}

extern "C" void kernel_launch(void* const* d_in, const int* in_sizes, int n_in,
                              void* d_out, int out_size, void* d_ws, size_t ws_size,
                              hipStream_t stream) {
    const float* tar_state = (const float*)d_in[0];
    const int*   tar_func  = (const int*)d_in[1];
    const float* ref_state = (const float*)d_in[2];
    const int*   ref_func  = (const int*)d_in[3];
    float* out = (float*)d_out;

    if (ws_size >= WS_NEED) {
        float* wsum = (float*)d_ws;
        int*   wcnt = (int*)((char*)d_ws + WCNT_OFF_B);
        emenc_stage1<<<NBLK1, 256, 0, stream>>>(tar_state, tar_func,
                                                ref_state, ref_func, wsum, wcnt);
        emenc_stage2<<<264 * 6, 128, 0, stream>>>(wsum, wcnt, out);
    } else {
        emenc_single<<<264, 256, 0, stream>>>(tar_state, tar_func,
                                              ref_state, ref_func, out);
    }
}

// Round 6
// 207.768 us; speedup vs baseline: 1.1202x; 1.0142x over previous
//
#include <hip/hip_runtime.h>

// Shapes: tarsent [8,512,512] f32, tar_func [8,512] i32,
//         refsent [8,32,256,512] f32, ref_func [8,32,256] i32.
// Output flat-concat f32 (masks as 0.0/1.0):
//   tar_aug[8,5,512]@0  tar_aug_mask[8,5]@20480  ref_aug[8,32,5,512]@20520
//   ref_aug_mask[8,32,5]@675880  tarpaper[8,512]@677160  tar_mask2[8]@681256
//   refpaper[8,32,512]@681264  ref_mask2[8,32]@812336   total 812592

#define H      512
#define HV     128
#define NL     5
#define BIGF   1e11f
#define CHUNK  64          // sentences per stage-1 block
#define RPC    8           // rows staged to LDS per inner chunk (16 KB)

#define OFF_TAR_AUG       0
#define OFF_TAR_AUG_MASK  20480
#define OFF_REF_AUG       20520
#define OFF_REF_AUG_MASK  675880
#define OFF_TARPAPER      677160
#define OFF_TAR_MASK2     681256
#define OFF_REFPAPER      681264
#define OFF_REF_MASK2     812336

#define NCHUNK_REF 4       // 256 / 64
#define NCHUNK_TAR 8       // 512 / 64
#define NBLK_REF   1024    // 256 segs * 4
#define NBLK1      1088    // + 8 segs * 8
#define WSUM_ELEMS ((size_t)NBLK1 * NL * H)      // 11.1 MB
#define WCNT_OFF_B (WSUM_ELEMS * 4)
#define WS_NEED    (WCNT_OFF_B + (size_t)NBLK1 * NL * 4)

__device__ inline float4 f4add(float4 a, float4 b) {
    a.x += b.x; a.y += b.y; a.z += b.z; a.w += b.w; return a;
}
__device__ inline float4 f4scale(float4 a, float s) {
    a.x *= s; a.y *= s; a.z *= s; a.w *= s; return a;
}
__device__ inline float4 f4fma(float w, float4 v, float4 a) {
    a.x = fmaf(w, v.x, a.x); a.y = fmaf(w, v.y, a.y);
    a.z = fmaf(w, v.z, a.z); a.w = fmaf(w, v.w, a.w); return a;
}
// Direct global->LDS DMA, 16 B per lane. LDS dest = uniform base + lane*16.
__device__ inline void async_copy16(const float* g, float* l) {
    __builtin_amdgcn_global_load_lds(
        (const __attribute__((address_space(1))) void*)g,
        (__attribute__((address_space(3))) void*)l, 16, 0, 0);
}

// ---------------- Stage 1: per-(segment,chunk) partial label sums ----------
// Ballot-compacts non-pad rows (label!=0), stages RPC rows at a time into LDS
// via global_load_lds, consumes branchlessly with cndmask-weighted FMAs.
__global__ __launch_bounds__(256) void emenc_stage1(
    const float* __restrict__ tar_state, const int* __restrict__ tar_func,
    const float* __restrict__ ref_state, const int* __restrict__ ref_func,
    float* __restrict__ wsum, int* __restrict__ wcnt)
{
    __shared__ float  sbuf[RPC * H];     // 16 KB staging buffer
    __shared__ float4 spart[HV * NL];    // 10 KB phase-combine
    __shared__ int    crow[CHUNK];       // compacted row indices
    __shared__ int    clab[CHUNK];       // compacted labels
    __shared__ int    scnt5[NL];
    __shared__ int    sm;

    const int b = blockIdx.x;
    const float* state;
    const int*   func;
    int s0;
    if (b < NBLK_REF) {
        const int seg = b >> 2, ch = b & 3;
        state = ref_state + (size_t)seg * 256 * H;
        func  = ref_func  + seg * 256;
        s0    = ch * CHUNK;
    } else {
        const int q = b - NBLK_REF;
        const int seg = q >> 3, ch = q & 7;
        state = tar_state + (size_t)seg * 512 * H;
        func  = tar_func  + seg * 512;
        s0    = ch * CHUNK;
    }

    const int tid = threadIdx.x;

    // Wave 0 (tids 0..63, exactly one wave): load labels, counts + compaction
    // via ballots.
    if (tid < CHUNK) {
        const int l = func[s0 + tid];
        #pragma unroll
        for (int q = 1; q <= NL; ++q) {
            const unsigned long long mq = __ballot(l == q);
            if (tid == 0) scnt5[q - 1] = (int)__popcll(mq);
        }
        const unsigned long long mask = __ballot(l != 0);
        if (l != 0) {
            const int pos = (int)__popcll(mask & ((1ull << tid) - 1ull));
            crow[pos] = tid;
            clab[pos] = l;
        }
        if (tid == 0) sm = (int)__popcll(mask);
    }
    __syncthreads();

    const int m     = sm;                 // non-pad rows in this chunk
    const int col   = tid & (HV - 1);
    const int phase = tid >> 7;
    const int lane  = tid & 63;
    const int wv    = tid >> 6;           // wave id 0..3

    float4 a1 = {0,0,0,0}, a2 = {0,0,0,0}, a3 = {0,0,0,0},
           a4 = {0,0,0,0}, a5 = {0,0,0,0};

    const int nch = (m + RPC - 1) / RPC;
    for (int c = 0; c < nch; ++c) {
        const int r0   = c * RPC;
        const int rem  = m - r0;
        const int rows = rem < RPC ? rem : RPC;   // block-uniform

        // Stage `rows` rows (2 KB each) as 2 half-row DMAs; wave wv issues
        // slots j = 4*wv .. 4*wv+3 of the 16 half-row slots.
        #pragma unroll
        for (int k = 0; k < 4; ++k) {
            const int j  = wv * 4 + k;     // wave-uniform
            const int rs = j >> 1;         // row slot 0..7
            if (rs < rows) {
                const int half = j & 1;
                const int row  = crow[r0 + rs];
                const float* g = state + (size_t)(s0 + row) * H
                                 + half * 256 + lane * 4;
                float* l = sbuf + rs * H + half * 256;
                async_copy16(g, l);
            }
        }
        __builtin_amdgcn_s_waitcnt(0xF70);  // vmcnt(0); exp/lgkm free
        __syncthreads();

        // Consume: thread handles rows phase, phase+2, ... of this chunk.
        for (int r = phase; r < rows; r += 2) {
            const int l = clab[r0 + r];
            const float4 v = *(const float4*)(sbuf + r * H + col * 4);
            a1 = f4fma((l == 1) ? 1.0f : 0.0f, v, a1);
            a2 = f4fma((l == 2) ? 1.0f : 0.0f, v, a2);
            a3 = f4fma((l == 3) ? 1.0f : 0.0f, v, a3);
            a4 = f4fma((l == 4) ? 1.0f : 0.0f, v, a4);
            a5 = f4fma((l == 5) ? 1.0f : 0.0f, v, a5);
        }
        __syncthreads();   // buffer reuse
    }

    // Phase combine + write partials.
    if (phase == 1) {
        spart[col * NL + 0] = a1;
        spart[col * NL + 1] = a2;
        spart[col * NL + 2] = a3;
        spart[col * NL + 3] = a4;
        spart[col * NL + 4] = a5;
    }
    __syncthreads();

    if (phase == 0) {
        a1 = f4add(a1, spart[col * NL + 0]);
        a2 = f4add(a2, spart[col * NL + 1]);
        a3 = f4add(a3, spart[col * NL + 2]);
        a4 = f4add(a4, spart[col * NL + 3]);
        a5 = f4add(a5, spart[col * NL + 4]);

        float* wb = wsum + (size_t)b * NL * H;
        ((float4*)(wb + 0 * H))[col] = a1;
        ((float4*)(wb + 1 * H))[col] = a2;
        ((float4*)(wb + 2 * H))[col] = a3;
        ((float4*)(wb + 3 * H))[col] = a4;
        ((float4*)(wb + 4 * H))[col] = a5;
    }
    if (tid < NL) wcnt[b * NL + tid] = scnt5[tid];
}

// ---------------- Stage 2: one block per (segment, role) ------------------
__global__ __launch_bounds__(128) void emenc_stage2(
    const float* __restrict__ wsum, const int* __restrict__ wcnt,
    float* __restrict__ out)
{
    const int bb   = blockIdx.x;
    const int seg  = bb / 6;
    const int role = bb - seg * 6;

    int nch, wb0;
    float *aug, *augmask, *paper, *mask2;
    if (seg < 256) {
        nch = NCHUNK_REF; wb0 = seg * NCHUNK_REF;
        aug     = out + OFF_REF_AUG      + (size_t)seg * NL * H;
        augmask = out + OFF_REF_AUG_MASK + seg * NL;
        paper   = out + OFF_REFPAPER     + (size_t)seg * H;
        mask2   = out + OFF_REF_MASK2    + seg;
    } else {
        const int q = seg - 256;
        nch = NCHUNK_TAR; wb0 = NBLK_REF + q * NCHUNK_TAR;
        aug     = out + OFF_TAR_AUG      + (size_t)q * NL * H;
        augmask = out + OFF_TAR_AUG_MASK + q * NL;
        paper   = out + OFF_TARPAPER     + (size_t)q * H;
        mask2   = out + OFF_TAR_MASK2    + q;
    }

    const int col = threadIdx.x;

    if (role < NL) {
        int c = 0;
        for (int ch = 0; ch < nch; ch++) c += wcnt[(wb0 + ch) * NL + role];
        float4 s = {0,0,0,0};
        for (int ch = 0; ch < nch; ch++)
            s = f4add(s, ((const float4*)(wsum + (size_t)(wb0 + ch) * NL * H
                                          + (size_t)role * H))[col]);
        const float inv = 1.0f / (c > 0 ? (float)c : BIGF);
        ((float4*)(aug + (size_t)role * H))[col] = f4scale(s, inv);
        if (col == 0) augmask[role] = c > 0 ? 1.0f : 0.0f;
    } else {
        int ct = 0;
        for (int ch = 0; ch < nch; ch++) {
            #pragma unroll
            for (int l = 0; l < NL; l++) ct += wcnt[(wb0 + ch) * NL + l];
        }
        float4 t = {0,0,0,0};
        for (int ch = 0; ch < nch; ch++) {
            const float4* wb = (const float4*)(wsum + (size_t)(wb0 + ch) * NL * H);
            #pragma unroll
            for (int l = 0; l < NL; l++) t = f4add(t, wb[l * HV + col]);
        }
        ((float4*)paper)[col] = f4scale(t, 1.0f / (ct > 0 ? (float)ct : BIGF));
        if (col == 0) mask2[0] = ct > 0 ? 1.0f : 0.0f;
    }
}

// ---------------- Fallback (single-stage) if ws too small ------------------
__global__ __launch_bounds__(256) void emenc_single(
    const float* __restrict__ tar_state, const int* __restrict__ tar_func,
    const float* __restrict__ ref_state, const int* __restrict__ ref_func,
    float* __restrict__ out)
{
    __shared__ int    sfunc[512];
    __shared__ float4 spart[HV * NL];
    __shared__ int    scnt[NL];

    const int b = blockIdx.x;
    const float* state;
    const int*   func;
    int S;
    float *aug, *augmask, *paper, *mask2;

    if (b < 256) {
        state   = ref_state + (size_t)b * 256 * H;
        func    = ref_func  + b * 256;
        S       = 256;
        aug     = out + OFF_REF_AUG      + (size_t)b * NL * H;
        augmask = out + OFF_REF_AUG_MASK + b * NL;
        paper   = out + OFF_REFPAPER     + (size_t)b * H;
        mask2   = out + OFF_REF_MASK2    + b;
    } else {
        const int q = b - 256;
        state   = tar_state + (size_t)q * 512 * H;
        func    = tar_func  + q * 512;
        S       = 512;
        aug     = out + OFF_TAR_AUG      + (size_t)q * NL * H;
        augmask = out + OFF_TAR_AUG_MASK + q * NL;
        paper   = out + OFF_TARPAPER     + (size_t)q * H;
        mask2   = out + OFF_TAR_MASK2    + q;
    }

    const int tid = threadIdx.x;
    for (int i = tid; i < S; i += 256) sfunc[i] = func[i];
    __syncthreads();

    const int col   = tid & (HV - 1);
    const int phase = tid >> 7;

    float4 a1 = {0,0,0,0}, a2 = {0,0,0,0}, a3 = {0,0,0,0},
           a4 = {0,0,0,0}, a5 = {0,0,0,0};

    for (int s = phase; s < S; s += 2) {
        float4 v = ((const float4*)(state + (size_t)s * H))[col];
        const int l = sfunc[s];
        a1 = f4fma((l == 1) ? 1.0f : 0.0f, v, a1);
        a2 = f4fma((l == 2) ? 1.0f : 0.0f, v, a2);
        a3 = f4fma((l == 3) ? 1.0f : 0.0f, v, a3);
        a4 = f4fma((l == 4) ? 1.0f : 0.0f, v, a4);
        a5 = f4fma((l == 5) ? 1.0f : 0.0f, v, a5);
    }

    if (phase == 1) {
        spart[col * NL + 0] = a1;
        spart[col * NL + 1] = a2;
        spart[col * NL + 2] = a3;
        spart[col * NL + 3] = a4;
        spart[col * NL + 4] = a5;
    }
    if (tid < NL) {
        int c = 0;
        for (int i = 0; i < S; ++i) c += (sfunc[i] == tid + 1) ? 1 : 0;
        scnt[tid] = c;
    }
    __syncthreads();

    if (phase == 0) {
        a1 = f4add(a1, spart[col * NL + 0]);
        a2 = f4add(a2, spart[col * NL + 1]);
        a3 = f4add(a3, spart[col * NL + 2]);
        a4 = f4add(a4, spart[col * NL + 3]);
        a5 = f4add(a5, spart[col * NL + 4]);

        const int c1 = scnt[0], c2 = scnt[1], c3 = scnt[2],
                  c4 = scnt[3], c5 = scnt[4];
        float4 t  = f4add(f4add(f4add(a1, a2), f4add(a3, a4)), a5);
        const int ct = c1 + c2 + c3 + c4 + c5;

        ((float4*)(aug + 0 * H))[col] = f4scale(a1, 1.0f / (c1 > 0 ? (float)c1 : BIGF));
        ((float4*)(aug + 1 * H))[col] = f4scale(a2, 1.0f / (c2 > 0 ? (float)c2 : BIGF));
        ((float4*)(aug + 2 * H))[col] = f4scale(a3, 1.0f / (c3 > 0 ? (float)c3 : BIGF));
        ((float4*)(aug + 3 * H))[col] = f4scale(a4, 1.0f / (c4 > 0 ? (float)c4 : BIGF));
        ((float4*)(aug + 4 * H))[col] = f4scale(a5, 1.0f / (c5 > 0 ? (float)c5 : BIGF));
        ((float4*)paper)[col]         = f4scale(t,  1.0f / (ct > 0 ? (float)ct : BIGF));

        if (col == 0) {
            augmask[0] = c1 > 0 ? 1.0f : 0.0f;
            augmask[1] = c2 > 0 ? 1.0f : 0.0f;
            augmask[2] = c3 > 0 ? 1.0f : 0.0f;
            augmask[3] = c4 > 0 ? 1.0f : 0.0f;
            augmask[4] = c5 > 0 ? 1.0f : 0.0f;
            mask2[0]   = ct > 0 ? 1.0f : 0.0f;
        }
    }
}

extern "C" void kernel_launch(void* const* d_in, const int* in_sizes, int n_in,
                              void* d_out, int out_size, void* d_ws, size_t ws_size,
                              hipStream_t stream) {
    const float* tar_state = (const float*)d_in[0];
    const int*   tar_func  = (const int*)d_in[1];
    const float* ref_state = (const float*)d_in[2];
    const int*   ref_func  = (const int*)d_in[3];
    float* out = (float*)d_out;

    if (ws_size >= WS_NEED) {
        float* wsum = (float*)d_ws;
        int*   wcnt = (int*)((char*)d_ws + WCNT_OFF_B);
        emenc_stage1<<<NBLK1, 256, 0, stream>>>(tar_state, tar_func,
                                                ref_state, ref_func, wsum, wcnt);
        emenc_stage2<<<264 * 6, 128, 0, stream>>>(wsum, wcnt, out);
    } else {
        emenc_single<<<264, 256, 0, stream>>>(tar_state, tar_func,
                                              ref_state, ref_func, out);
    }
}